// Round 1
// baseline (327.589 us; speedup 1.0000x reference)
//
#include <hip/hip_runtime.h>

// Quantization layer: per-band nearest-codebook lookup.
// x: (B=2, NBAND=40, C=64, T=1500) f32 ; codebook: (NBAND, 1024, C) f32 (rows ~unit-norm)
// out[b, band, c, t] = codebook[band, argmin_k(||x[b,band,:,t] - cb[band,k]||^2), c]
//
// Compute-bound: 7.86 G FMA fp32 (no fp32 MFMA on CDNA4). Register-tiled fp32 GEMM
// with fused running-argmin and fused gather/transpose epilogue.

#define NBATCH 2
#define NBAND  40
#define CH     64
#define TT     1500
#define NCODE  1024
#define TN     128   // t-tile per workgroup
#define KC     128   // code chunk per LDS stage
#define NTILE  12    // ceil(1500/128)

__global__ __launch_bounds__(256, 2)
void vq_argmin_kernel(const float* __restrict__ x,
                      const float* __restrict__ cb,
                      float* __restrict__ out) {
    // 32 KB x-tile [c][t], 32 KB codebook chunk transposed [c][k], 1 KB half-row norms
    __shared__ float XT_s[CH * TN];
    __shared__ float CBT_s[CH * KC];
    __shared__ float c2part[256];

    const int tile  = blockIdx.x;
    const int band  = blockIdx.y;
    const int batch = blockIdx.z;
    const int t0    = tile * TN;

    const int tid = threadIdx.x;
    const int tx  = tid & 15;   // t-group (16)
    const int ty  = tid >> 4;   // k-group (16)

    // ---- stage x tile: XT[c][t] = x[batch, band, c, t0+t] (coalesced along t) ----
    {
        const int c = tid >> 2;      // 0..63
        const int q = tid & 3;
        const float* src = x + ((size_t)(batch * NBAND + band) * CH + c) * TT + t0;
        #pragma unroll
        for (int i = 0; i < 8; ++i) {
            const int t = q * 32 + i * 4;
            float4 v = make_float4(0.f, 0.f, 0.f, 0.f);
            if (t0 + t < TT) v = *(const float4*)(src + t);   // TT%4==0 so quad-granular guard is exact
            *(float4*)&XT_s[c * TN + t] = v;
        }
    }

    float vmin[8];
    int   vidx[8];
    #pragma unroll
    for (int i = 0; i < 8; ++i) { vmin[i] = 3.4e38f; vidx[i] = 0x7fffffff; }

    for (int kc = 0; kc < NCODE; kc += KC) {
        __syncthreads();   // protect CBT/c2part from previous iteration's readers
        // ---- stage codebook chunk transposed + per-half-row sum of squares ----
        {
            const int k   = tid >> 1;            // 0..127
            const int ch0 = (tid & 1) * 32;      // c base: 0 or 32
            const float* src = cb + ((size_t)(band * NCODE + kc + k)) * CH + ch0;
            float s = 0.f;
            #pragma unroll
            for (int i = 0; i < 8; ++i) {
                const float4 v = *(const float4*)(src + i * 4);
                const int c0 = ch0 + i * 4;
                CBT_s[(c0 + 0) * KC + k] = v.x;
                CBT_s[(c0 + 1) * KC + k] = v.y;
                CBT_s[(c0 + 2) * KC + k] = v.z;
                CBT_s[(c0 + 3) * KC + k] = v.w;
                s = fmaf(v.x, v.x, s);
                s = fmaf(v.y, v.y, s);
                s = fmaf(v.z, v.z, s);
                s = fmaf(v.w, v.w, s);
            }
            c2part[tid] = s;
        }
        __syncthreads();

        // ---- 8x8 register-tile dot products over c ----
        float acc[8][8];
        #pragma unroll
        for (int ii = 0; ii < 8; ++ii)
            #pragma unroll
            for (int jj = 0; jj < 8; ++jj) acc[ii][jj] = 0.f;

        #pragma unroll 4
        for (int c = 0; c < CH; ++c) {
            const float4 xa0 = *(const float4*)&XT_s[c * TN + tx * 4];
            const float4 xa1 = *(const float4*)&XT_s[c * TN + 64 + tx * 4];
            const float4 cv0 = *(const float4*)&CBT_s[c * KC + ty * 4];
            const float4 cv1 = *(const float4*)&CBT_s[c * KC + 64 + ty * 4];
            const float xa[8] = {xa0.x, xa0.y, xa0.z, xa0.w, xa1.x, xa1.y, xa1.z, xa1.w};
            const float cv[8] = {cv0.x, cv0.y, cv0.z, cv0.w, cv1.x, cv1.y, cv1.z, cv1.w};
            #pragma unroll
            for (int ii = 0; ii < 8; ++ii)
                #pragma unroll
                for (int jj = 0; jj < 8; ++jj)
                    acc[ii][jj] = fmaf(xa[ii], cv[jj], acc[ii][jj]);
        }

        // ---- running argmin update (k strictly increasing within a thread -> strict '<' keeps first) ----
        #pragma unroll
        for (int jj = 0; jj < 8; ++jj) {
            const int kl    = (jj < 4) ? (ty * 4 + jj) : (64 + ty * 4 + (jj - 4));
            const float c2v = c2part[2 * kl] + c2part[2 * kl + 1];
            const int kglob = kc + kl;
            #pragma unroll
            for (int ii = 0; ii < 8; ++ii) {
                const float score = fmaf(-2.f, acc[ii][jj], c2v);  // dist minus const ||x||^2
                if (score < vmin[ii]) { vmin[ii] = score; vidx[ii] = kglob; }
            }
        }
    }

    __syncthreads();   // all XT reads done; alias XT_s for the reduction scratch
    float* redv = XT_s;                   // [TN][16]
    int*   redi = (int*)(XT_s + TN * 16); // [TN][16]
    int*   idxs = (int*)(XT_s + TN * 32); // [TN]

    #pragma unroll
    for (int ii = 0; ii < 8; ++ii) {
        const int t = (ii < 4) ? (tx * 4 + ii) : (64 + tx * 4 + (ii - 4));
        redv[t * 16 + ty] = vmin[ii];
        redi[t * 16 + ty] = vidx[ii];
    }
    __syncthreads();

    // one thread per t: reduce 16 partials; tie -> smallest k (jnp.argmin first-min rule)
    if (tid < TN) {
        float bv = redv[tid * 16];
        int   bi = redi[tid * 16];
        #pragma unroll
        for (int j = 1; j < 16; ++j) {
            const float v  = redv[tid * 16 + j];
            const int   id = redi[tid * 16 + j];
            if (v < bv || (v == bv && id < bi)) { bv = v; bi = id; }
        }
        idxs[tid] = bi;
    }
    __syncthreads();

    // ---- fused gather + transpose write: out[batch, band, c, t0+t] = cb[band, idx[t], c] ----
    {
        const int tloc  = tid & 127;
        const int chalf = tid >> 7;   // 0 or 1
        const int tg    = t0 + tloc;
        if (tg < TT) {
            const int idx = idxs[tloc];
            const float* crow = cb + ((size_t)(band * NCODE + idx)) * CH;
            float* obase = out + ((size_t)(batch * NBAND + band) * CH) * TT + tg;
            #pragma unroll
            for (int i = 0; i < 32; ++i) {
                const int c = chalf * 32 + i;
                obase[(size_t)c * TT] = crow[c];   // lanes differ in t -> coalesced store
            }
        }
    }
}

extern "C" void kernel_launch(void* const* d_in, const int* in_sizes, int n_in,
                              void* d_out, int out_size, void* d_ws, size_t ws_size,
                              hipStream_t stream) {
    const float* x  = (const float*)d_in[0];
    const float* cb = (const float*)d_in[1];
    float* out = (float*)d_out;
    dim3 grid(NTILE, NBAND, NBATCH);
    vq_argmin_kernel<<<grid, dim3(256), 0, stream>>>(x, cb, out);
}